// Round 4
// baseline (2014.999 us; speedup 1.0000x reference)
//
#include <hip/hip_runtime.h>

#define D_NODE 256
#define D_EDGE 128
#define D_U    128
#define HID    512
#define D_OUT  128
#define NB     512
#define EPS    1e-5f

// ---------------- workspace layout (bytes) ----------------
// 0        : e_sums   [NB][D_EDGE] f32   (262144 B)
// 262144   : e_cnt    [NB] u32           (2048 B)
// 264192   : x_mean   [NB][D_NODE] f32   (524288 B)
// 788480   : H        [NB][HID] f32      (1048576 B)
// 1837056  : colsum   [HID] f32          (2048 B)
// 1839104  : colsumsq [HID] f32          (2048 B)

// Edge scatter-sum: 2 column-groups of 64 cols; per-block LDS accumulator
// [512 segs][64 cols] f32 with stride 65 (bank-conflict break), LDS atomics,
// then one global atomic flush per block.
__global__ __launch_bounds__(1024) void edge_aggr_kernel(
    const float* __restrict__ edge_attr, const int* __restrict__ col,
    const int* __restrict__ batch, float* __restrict__ e_sums,
    unsigned int* __restrict__ e_cnt, int E)
{
    __shared__ float lds[NB * 65];
    __shared__ unsigned int lcnt[NB];
    const int t = threadIdx.x;
    const int g = blockIdx.x & 1;       // column group (0: cols 0-63, 1: 64-127)
    const int chunk = blockIdx.x >> 1;  // edge chunk
    const int nchunks = gridDim.x >> 1;

    for (int i = t; i < NB * 65; i += 1024) lds[i] = 0.f;
    for (int i = t; i < NB; i += 1024) lcnt[i] = 0u;
    __syncthreads();

    const long long per = ((long long)E + nchunks - 1) / nchunks;
    long long e0 = (long long)chunk * per;
    long long e1 = e0 + per; if (e1 > E) e1 = E;

    const int sub = t >> 4;             // 64 edges in flight per iteration
    const int c4  = (t & 15) << 2;      // column offset within group

    for (long long e = e0 + sub; e < e1; e += 64) {
        const int cnode = col[e];
        const int seg   = batch[cnode];
        const float4 v = *reinterpret_cast<const float4*>(
            edge_attr + e * 128 + g * 64 + c4);
        float* dst = lds + seg * 65 + c4;
        atomicAdd(dst + 0, v.x);
        atomicAdd(dst + 1, v.y);
        atomicAdd(dst + 2, v.z);
        atomicAdd(dst + 3, v.w);
        if (g == 0 && c4 == 0) atomicAdd(&lcnt[seg], 1u);
    }
    __syncthreads();

    for (int i = t; i < NB * 64; i += 1024) {
        const int seg = i >> 6, c = i & 63;
        atomicAdd(&e_sums[seg * 128 + g * 64 + c], lds[seg * 65 + c]);
    }
    if (g == 0)
        for (int i = t; i < NB; i += 1024) atomicAdd(&e_cnt[i], lcnt[i]);
}

// Node scatter-mean: batch is sorted -> block b binary-searches its row range,
// sums directly (no atomics). 256 threads = 256 columns.
__global__ __launch_bounds__(256) void node_aggr_kernel(
    const float* __restrict__ x, const int* __restrict__ batch,
    float* __restrict__ x_mean, int N)
{
    const int b = blockIdx.x;
    int lo = 0, hi = N;
    while (lo < hi) { int m = (lo + hi) >> 1; if (batch[m] < b) lo = m + 1; else hi = m; }
    const int s = lo;
    lo = s; hi = N;
    while (lo < hi) { int m = (lo + hi) >> 1; if (batch[m] < b + 1) lo = m + 1; else hi = m; }
    const int epos = lo;

    float acc = 0.f;
    for (int r = s; r < epos; ++r) acc += x[(long long)r * D_NODE + threadIdx.x];
    const float cnt = (float)(epos - s);
    x_mean[b * D_NODE + threadIdx.x] = acc / fmaxf(cnt, 1.f);
}

// H = concat(u, x_mean, e_mean) @ W1 + b1   -> [NB][HID]
__global__ __launch_bounds__(512) void h_kernel(
    const float* __restrict__ u, const float* __restrict__ x_mean,
    const float* __restrict__ e_sums, const unsigned int* __restrict__ e_cnt,
    const float* __restrict__ W1, const float* __restrict__ b1,
    float* __restrict__ H)
{
    __shared__ float a[512];
    const int b = blockIdx.x, j = threadIdx.x;
    if (j < 128)      a[j] = u[b * 128 + j];
    else if (j < 384) a[j] = x_mean[b * 256 + (j - 128)];
    else {
        const float cnt = fmaxf((float)e_cnt[b], 1.f);
        a[j] = e_sums[b * 128 + (j - 384)] / cnt;
    }
    __syncthreads();

    float acc = b1[j];
#pragma unroll 8
    for (int k = 0; k < 512; ++k) acc += a[k] * W1[k * 512 + j];
    H[b * 512 + j] = acc;
}

// Per-column sum / sumsq over the 512 rows of H.
__global__ __launch_bounds__(512) void stats_kernel(
    const float* __restrict__ H, float* __restrict__ colsum,
    float* __restrict__ colsumsq)
{
    const int j = threadIdx.x;
    const int r0 = blockIdx.x * 32;
    float s = 0.f, ss = 0.f;
#pragma unroll 4
    for (int r = 0; r < 32; ++r) {
        const float v = H[(r0 + r) * 512 + j];
        s += v; ss += v * v;
    }
    atomicAdd(&colsum[j], s);
    atomicAdd(&colsumsq[j], ss);
}

// out = relu(batchnorm(H)) @ W2 + b2
__global__ __launch_bounds__(128) void out_kernel(
    const float* __restrict__ H, const float* __restrict__ colsum,
    const float* __restrict__ colsumsq, const float* __restrict__ gamma,
    const float* __restrict__ beta, const float* __restrict__ W2,
    const float* __restrict__ b2, float* __restrict__ out)
{
    __shared__ float n[512];
    const int b = blockIdx.x, j = threadIdx.x;
    for (int k = j; k < 512; k += 128) {
        const float m   = colsum[k] * (1.f / 512.f);
        const float var = colsumsq[k] * (1.f / 512.f) - m * m;
        const float inv = rsqrtf(var + EPS);
        const float v   = (H[b * 512 + k] - m) * inv * gamma[k] + beta[k];
        n[k] = fmaxf(v, 0.f);
    }
    __syncthreads();

    float acc = b2[j];
#pragma unroll 8
    for (int k = 0; k < 512; ++k) acc += n[k] * W2[k * 128 + j];
    out[b * 128 + j] = acc;
}

extern "C" void kernel_launch(void* const* d_in, const int* in_sizes, int n_in,
                              void* d_out, int out_size, void* d_ws, size_t ws_size,
                              hipStream_t stream)
{
    const float* x          = (const float*)d_in[0];
    const int*   edge_index = (const int*)d_in[1];   // [2][E], int32 per harness
    const float* edge_attr  = (const float*)d_in[2];
    const float* u          = (const float*)d_in[3];
    const int*   batch      = (const int*)d_in[4];
    const float* W1         = (const float*)d_in[5];
    const float* b1         = (const float*)d_in[6];
    const float* gamma      = (const float*)d_in[7];
    const float* beta       = (const float*)d_in[8];
    const float* W2         = (const float*)d_in[9];
    const float* b2         = (const float*)d_in[10];
    float* out = (float*)d_out;

    const int N = in_sizes[0] / D_NODE;
    const int E = in_sizes[1] / 2;

    char* ws = (char*)d_ws;
    float*        e_sums   = (float*)(ws + 0);
    unsigned int* e_cnt    = (unsigned int*)(ws + 262144);
    float*        x_mean   = (float*)(ws + 264192);
    float*        H        = (float*)(ws + 788480);
    float*        colsum   = (float*)(ws + 1837056);
    float*        colsumsq = (float*)(ws + 1839104);

    // zero the atomic accumulators (ws is poisoned to 0xAA before every call)
    hipMemsetAsync(ws, 0, 264192, stream);
    hipMemsetAsync(ws + 1837056, 0, 4096, stream);

    const int* col = edge_index + E;  // second row of edge_index

    edge_aggr_kernel<<<256, 1024, 0, stream>>>(edge_attr, col, batch, e_sums, e_cnt, E);
    node_aggr_kernel<<<NB, 256, 0, stream>>>(x, batch, x_mean, N);
    h_kernel<<<NB, 512, 0, stream>>>(u, x_mean, e_sums, e_cnt, W1, b1, H);
    stats_kernel<<<16, 512, 0, stream>>>(H, colsum, colsumsq);
    out_kernel<<<NB, 128, 0, stream>>>(H, colsum, colsumsq, gamma, beta, W2, b2, out);
}